// Round 1
// 93.348 us; speedup vs baseline: 1.0453x; 1.0453x over previous
//
#include <hip/hip_runtime.h>

#define NU_C 0.3f
#define EQ_W 0.1f
#define EN_W 0.1f

// Structured-grid formulation: R is a constant-coefficient 7-point stencil
// gather; energy is per-cell. No atomics (R2: same-address atomics = ~107us).
// This round: 2 nodes per thread (even j0) — 5 float4 + 7 float2 loads serve
// both nodes (vs 24 float2), 16B/lane coalescing, 2048 blocks / 2048 partials.

__device__ __forceinline__ void node_residual(
    bool i0, bool iok, bool jn0, bool jok,
    float k, float q, float fC, float hs,
    float2 Uc, float2 Ue, float2 Uw, float2 Un,
    float2 Us, float2 Usw, float2 Une,
    float& r2_acc)
{
    float fx = 0.f, fy = 0.f;
    float e0, e1, e2, s0, s1, s2;

    // T1: tri1(i,j), A=Uc B=Ue C=Us, center = node a
    if (iok && jok) {
        e0 = k * (Us.x - Uc.x);
        e1 = k * (Ue.y - Uc.y);
        e2 = k * ((Ue.x - Uc.x) + (Us.y - Uc.y));
        s0 = fC * (e0 + NU_C * e1); s1 = fC * (NU_C * e0 + e1); s2 = fC * hs * e2;
        fx -= q * (s0 + s2); fy -= q * (s1 + s2);
    }
    // T2: tri1(i,j-1), A=Uw B=Uc C=Usw, center = node b
    if (iok && jn0) {
        e0 = k * (Usw.x - Uw.x);
        e1 = k * (Uc.y - Uw.y);
        e2 = k * ((Uc.x - Uw.x) + (Usw.y - Uw.y));
        s0 = fC * (e0 + NU_C * e1); s1 = fC * (NU_C * e0 + e1); s2 = fC * hs * e2;
        fx += q * s2; fy += q * s1;
    }
    // T3: tri1(i-1,j), A=Un B=Une C=Uc, center = node c
    if (i0 && jok) {
        e0 = k * (Uc.x - Un.x);
        e1 = k * (Une.y - Un.y);
        e2 = k * ((Une.x - Un.x) + (Uc.y - Un.y));
        s0 = fC * (e0 + NU_C * e1); s1 = fC * (NU_C * e0 + e1); s2 = fC * hs * e2;
        fx += q * s0; fy += q * s2;
    }
    // T4: tri2(i,j-1), B=Uc D=Us C=Usw, center = node b
    if (iok && jn0) {
        e0 = k * (Us.x - Uc.x);
        e1 = k * (Us.y - Usw.y);
        e2 = k * ((Us.x - Usw.x) + (Us.y - Uc.y));
        s0 = fC * (e0 + NU_C * e1); s1 = fC * (NU_C * e0 + e1); s2 = fC * hs * e2;
        fx -= q * s0; fy -= q * s2;
    }
    // T5: tri2(i-1,j-1), B=Un D=Uc C=Uw, center = node d
    if (i0 && jn0) {
        e0 = k * (Uc.x - Un.x);
        e1 = k * (Uc.y - Uw.y);
        e2 = k * ((Uc.x - Uw.x) + (Uc.y - Un.y));
        s0 = fC * (e0 + NU_C * e1); s1 = fC * (NU_C * e0 + e1); s2 = fC * hs * e2;
        fx += q * (s0 + s2); fy += q * (s1 + s2);
    }
    // T6: tri2(i-1,j), B=Une D=Ue C=Uc, center = node c
    if (i0 && jok) {
        e0 = k * (Ue.x - Une.x);
        e1 = k * (Ue.y - Uc.y);
        e2 = k * ((Ue.x - Uc.x) + (Ue.y - Une.y));
        s0 = fC * (e0 + NU_C * e1); s1 = fC * (NU_C * e0 + e1); s2 = fC * hs * e2;
        fx -= q * s2; fy -= q * s1;
    }

    r2_acc += fx * fx + fy * fy;
}

__device__ __forceinline__ void cell_energy(
    float k, float area, float fC, float hs,
    float2 Uc, float2 Ue, float2 Us, float2 Use,
    float2 Tc, float2 Te, float2 Ts, float2 Tse,
    float& energy)
{
    const float dcx = Uc.x - Tc.x,   dcy = Uc.y - Tc.y;
    const float dex = Ue.x - Te.x,   dey = Ue.y - Te.y;
    const float dsx = Us.x - Ts.x,   dsy = Us.y - Ts.y;
    const float dqx = Use.x - Tse.x, dqy = Use.y - Tse.y;
    float e0, e1, e2;
    // tri1: A=dc B=de C=ds
    e0 = k * (dsx - dcx);
    e1 = k * (dey - dcy);
    e2 = k * ((dex - dcx) + (dsy - dcy));
    energy += area * fC * (e0 * e0 + 2.f * NU_C * e0 * e1 + e1 * e1 + hs * e2 * e2);
    // tri2: B=de D=dq C=ds
    e0 = k * (dqx - dex);
    e1 = k * (dqy - dsy);
    e2 = k * ((dqx - dsx) + (dqy - dey));
    energy += area * fC * (e0 * e0 + 2.f * NU_C * e0 * e1 + e1 * e1 + hs * e2 * e2);
}

__global__ __launch_bounds__(256)
void pino_stencil_kernel(const float2* __restrict__ up,
                         const float2* __restrict__ ut,
                         float2* __restrict__ partials,
                         int g, float k, float q, float area) {
    const float fC = 1.f / (1.f - NU_C * NU_C);   // plane-stress factor
    const float hs = (1.f - NU_C) * 0.5f;          // C[2][2] / fC

    const int lane = threadIdx.x & 63;
    const int wv = threadIdx.x >> 6;
    const int ja = (blockIdx.x * 64 + lane) * 2;   // even column, node A
    const int jb = ja + 1;                          // node B
    const int i = blockIdx.y * 4 + wv;

    float r2 = 0.f, energy = 0.f;

    if (i < g && ja < g) {
        const int im = (i > 0) ? i - 1 : 0;
        const int ip = (i < g - 1) ? i + 1 : g - 1;
        const int jm = (ja > 0) ? ja - 1 : 0;
        const int jp2 = (ja + 2 < g) ? ja + 2 : g - 1;
        const bool i0 = (i > 0), iok = (i < g - 1);
        const bool hasB = (jb < g);
        const bool jokB = (jb < g - 1);            // jokA == hasB; jn0A = ja>0; jn0B = true

        const size_t rI  = (size_t)i  * g;
        const size_t rIm = (size_t)im * g;
        const size_t rIp = (size_t)ip * g;

        float4 Ui, Uim, Uip, Ti, Tip;
        if (hasB) {
            const float4* up4 = reinterpret_cast<const float4*>(up);
            const float4* ut4 = reinterpret_cast<const float4*>(ut);
            Ui  = up4[(rI  + ja) >> 1];
            Uim = up4[(rIm + ja) >> 1];
            Uip = up4[(rIp + ja) >> 1];
            Ti  = ut4[(rI  + ja) >> 1];
            Tip = ut4[(rIp + ja) >> 1];
        } else {                                    // odd-g tail only
            float2 t;
            t = up[rI  + ja]; Ui  = make_float4(t.x, t.y, t.x, t.y);
            t = up[rIm + ja]; Uim = make_float4(t.x, t.y, t.x, t.y);
            t = up[rIp + ja]; Uip = make_float4(t.x, t.y, t.x, t.y);
            t = ut[rI  + ja]; Ti  = make_float4(t.x, t.y, t.x, t.y);
            t = ut[rIp + ja]; Tip = make_float4(t.x, t.y, t.x, t.y);
        }
        const float2 Uw1 = up[rI  + jm];            // (i, ja-1)
        const float2 Ue2 = up[rI  + jp2];           // (i, ja+2)
        const float2 Un2 = up[rIm + jp2];           // (im, ja+2)
        const float2 Usm = up[rIp + jm];            // (ip, ja-1)
        const float2 Us2 = up[rIp + jp2];           // (ip, ja+2)
        const float2 Tt2 = ut[rI  + jp2];
        const float2 Ts2 = ut[rIp + jp2];

        const float2 UiA  = make_float2(Ui.x,  Ui.y),  UiB  = make_float2(Ui.z,  Ui.w);
        const float2 UimA = make_float2(Uim.x, Uim.y), UimB = make_float2(Uim.z, Uim.w);
        const float2 UipA = make_float2(Uip.x, Uip.y), UipB = make_float2(Uip.z, Uip.w);
        const float2 TiA  = make_float2(Ti.x,  Ti.y),  TiB  = make_float2(Ti.z,  Ti.w);
        const float2 TipA = make_float2(Tip.x, Tip.y), TipB = make_float2(Tip.z, Tip.w);

        // ---- node A: Uc=UiA Ue=UiB Uw=Uw1 Un=UimA Us=UipA Usw=Usm Une=UimB
        node_residual(i0, iok, (ja > 0), hasB, k, q, fC, hs,
                      UiA, UiB, Uw1, UimA, UipA, Usm, UimB, r2);
        // cell (i, ja): gate iok && (ja < g-1) == iok && hasB
        if (iok && hasB) {
            cell_energy(k, area, fC, hs,
                        UiA, UiB, UipA, UipB,
                        TiA, TiB, TipA, TipB, energy);
        }

        // ---- node B: Uc=UiB Ue=Ue2 Uw=UiA Un=UimB Us=UipB Usw=UipA Une=Un2
        if (hasB) {
            node_residual(i0, iok, true, jokB, k, q, fC, hs,
                          UiB, Ue2, UiA, UimB, UipB, UipA, Un2, r2);
            if (iok && jokB) {
                cell_energy(k, area, fC, hs,
                            UiB, Ue2, UipB, Us2,
                            TiB, Tt2, TipB, Ts2, energy);
            }
        }
    }

    // block reduction (wave shuffle + LDS across 4 waves), then ONE float2
    // store per block — no atomics.
    for (int o = 32; o > 0; o >>= 1) {
        r2     += __shfl_down(r2, o, 64);
        energy += __shfl_down(energy, o, 64);
    }
    __shared__ float s_r[4], s_e[4];
    if (lane == 0) { s_r[wv] = r2; s_e[wv] = energy; }
    __syncthreads();
    if (threadIdx.x == 0) {
        const int b = blockIdx.y * gridDim.x + blockIdx.x;
        partials[b] = make_float2(s_r[0] + s_r[1] + s_r[2] + s_r[3],
                                  s_e[0] + s_e[1] + s_e[2] + s_e[3]);
    }
}

__global__ __launch_bounds__(256)
void pino_reduce_kernel(const float2* __restrict__ partials,
                        float* __restrict__ out,
                        int nblocks, float inv_n2, float inv_ta) {
    float r = 0.f, e = 0.f;
    for (int b = threadIdx.x; b < nblocks; b += 256) {
        float2 p = partials[b];
        r += p.x;
        e += p.y;
    }
    for (int o = 32; o > 0; o >>= 1) {
        r += __shfl_down(r, o, 64);
        e += __shfl_down(e, o, 64);
    }
    __shared__ float sr[4], se[4];
    const int lane = threadIdx.x & 63;
    const int wv = threadIdx.x >> 6;
    if (lane == 0) { sr[wv] = r; se[wv] = e; }
    __syncthreads();
    if (threadIdx.x == 0) {
        out[0] = EQ_W * (sr[0] + sr[1] + sr[2] + sr[3]) * inv_n2 +
                 EN_W * (se[0] + se[1] + se[2] + se[3]) * inv_ta;
    }
}

extern "C" void kernel_launch(void* const* d_in, const int* in_sizes, int n_in,
                              void* d_out, int out_size, void* d_ws, size_t ws_size,
                              hipStream_t stream) {
    const float2* up = (const float2*)d_in[0];
    const float2* ut = (const float2*)d_in[1];
    const int N = in_sizes[0] / 2;           // nodes = g*g

    int g = 1;
    while (g * g < N) g++;                   // g = 1024

    const double h = 1.0 / (double)(g - 1);
    const float k = (float)((double)(g - 1));         // 1/h
    const float area = (float)(0.5 * h * h);          // per-triangle area
    const float q = (float)(0.5 * h);                 // area * k
    const double M = 2.0 * (double)(g - 1) * (double)(g - 1);
    const float inv_total_area = (float)(1.0 / (M * 0.5 * h * h));  // = 1.0
    const float inv_n2 = (float)(1.0 / (2.0 * (double)N));

    float2* partials = (float2*)d_ws;        // every slot overwritten -> no memset

    const int jpairs = (g + 1) / 2;          // nodes handled 2-per-thread in j
    dim3 blk(256);
    dim3 grid((jpairs + 63) / 64, (g + 3) / 4);
    const int nblocks = grid.x * grid.y;

    pino_stencil_kernel<<<grid, blk, 0, stream>>>(up, ut, partials, g, k, q, area);
    pino_reduce_kernel<<<1, blk, 0, stream>>>(partials, (float*)d_out,
                                              nblocks, inv_n2, inv_total_area);
}